// Round 4
// baseline (285.411 us; speedup 1.0000x reference)
//
#include <hip/hip_runtime.h>

#define THREADS 256
#define SAMPLES_PER_BLOCK 512   // 2 samples/thread

__device__ __forceinline__ float fast_sigmoid(float v) {
    float e = __expf(-v);
    return __builtin_amdgcn_rcpf(1.0f + e);
}

__global__ __launch_bounds__(THREADS) void olcnn_kernel(
    const float* __restrict__ x,
    const float* __restrict__ Wc, const float* __restrict__ bc,
    const float* __restrict__ Wh, const float* __restrict__ bh,
    const float* __restrict__ Wm, const float* __restrict__ bm,
    const float* __restrict__ Wo, const float* __restrict__ bo,
    float* __restrict__ out)
{
    // No LDS, no barrier, no fp16 round-trip. Each thread owns 2 samples and
    // reads its 27-float G-chunks directly; the wave's 128 samples are a
    // contiguous 41.5 KB region so every cache line is fully consumed via
    // L1/L2. lgkmcnt is SMEM-only -> weight s_loads pipeline cleanly.
    const int tid  = threadIdx.x;
    const int wave = tid >> 6, lane = tid & 63;
    // Wave-contiguous samples: s0 block of 64, s1 the adjacent block of 64.
    const int s0 = blockIdx.x * SAMPLES_PER_BLOCK + wave * 128 + lane;
    const int s1 = s0 + 64;

    const float* xA = x + s0 * 81;   // 524288*324B < 2^31: 32-bit math ok
    const float* xB = x + s1 * 81;

    float res[2][4];

    #pragma unroll
    for (int G = 0; G < 3; ++G) {
        // chunk-local layout: c[pr*9 + gc*3 + pc], 27 contiguous floats
        float c0[27], c1[27];
        #pragma unroll
        for (int j = 0; j < 27; ++j) c0[j] = xA[G * 27 + j];
        #pragma unroll
        for (int j = 0; j < 27; ++j) c1[j] = xB[G * 27 + j];

        float hb0[9], hb1[9];
        #pragma unroll
        for (int j = 0; j < 3; ++j) {            // patch g = 3G + j
            const int g = G * 3 + j;
            float ft0[9], ft1[9];
            #pragma unroll
            for (int k = 0; k < 9; ++k) {
                float a0 = bc[g * 9 + k], a1 = a0;
                #pragma unroll
                for (int pr = 0; pr < 3; ++pr)
                    #pragma unroll
                    for (int pc = 0; pc < 3; ++pc) {
                        const float w = Wc[(g * 9 + k) * 9 + pr * 3 + pc];
                        const int ci = pr * 9 + j * 3 + pc;
                        a0 = fmaf(c0[ci], w, a0);
                        a1 = fmaf(c1[ci], w, a1);
                    }
                ft0[k] = fast_sigmoid(a0);
                ft1[k] = fast_sigmoid(a1);
            }
            #pragma unroll
            for (int n = 0; n < 3; ++n) {
                float a0 = bh[g * 3 + n], a1 = a0;
                #pragma unroll
                for (int p = 0; p < 9; ++p) {
                    const float w = Wh[(g * 3 + n) * 9 + p];
                    a0 = fmaf(ft0[p], w, a0);
                    a1 = fmaf(ft1[p], w, a1);
                }
                hb0[j * 3 + n] = fast_sigmoid(a0);
                hb1[j * 3 + n] = fast_sigmoid(a1);
            }
        }

        float m0[4], m1[4];
        #pragma unroll
        for (int n = 0; n < 4; ++n) {
            float a0 = bm[G * 4 + n], a1 = a0;
            #pragma unroll
            for (int p = 0; p < 9; ++p) {
                const float w = Wm[(G * 4 + n) * 9 + p];
                a0 = fmaf(hb0[p], w, a0);
                a1 = fmaf(hb1[p], w, a1);
            }
            m0[n] = fast_sigmoid(a0);
            m1[n] = fast_sigmoid(a1);
        }

        // outputs reading middle group G (c % 3 == G): c = G, plus c = 3 for G = 0
        {
            float a0 = bo[G], a1 = a0;
            #pragma unroll
            for (int p = 0; p < 4; ++p) {
                const float w = Wo[G * 4 + p];
                a0 = fmaf(m0[p], w, a0);
                a1 = fmaf(m1[p], w, a1);
            }
            res[0][G] = a0; res[1][G] = a1;
        }
        if (G == 0) {
            float a0 = bo[3], a1 = a0;
            #pragma unroll
            for (int p = 0; p < 4; ++p) {
                const float w = Wo[3 * 4 + p];
                a0 = fmaf(m0[p], w, a0);
                a1 = fmaf(m1[p], w, a1);
            }
            res[0][3] = a0; res[1][3] = a1;
        }
    }

    float4 o0, o1;
    o0.x = res[0][0]; o0.y = res[0][1]; o0.z = res[0][2]; o0.w = res[0][3];
    o1.x = res[1][0]; o1.y = res[1][1]; o1.z = res[1][2]; o1.w = res[1][3];
    ((float4*)out)[s0] = o0;   // wave-contiguous 16B/lane stores
    ((float4*)out)[s1] = o1;
}

extern "C" void kernel_launch(void* const* d_in, const int* in_sizes, int n_in,
                              void* d_out, int out_size, void* d_ws, size_t ws_size,
                              hipStream_t stream) {
    const float* x  = (const float*)d_in[0];
    const float* Wc = (const float*)d_in[1];
    const float* bc = (const float*)d_in[2];
    const float* Wh = (const float*)d_in[3];
    const float* bh = (const float*)d_in[4];
    const float* Wm = (const float*)d_in[5];
    const float* bm = (const float*)d_in[6];
    const float* Wo = (const float*)d_in[7];
    const float* bo = (const float*)d_in[8];
    float* out = (float*)d_out;

    const int B = in_sizes[0] / 81;                    // 524288
    const int blocks = B / SAMPLES_PER_BLOCK;          // 1024 (exact)
    olcnn_kernel<<<blocks, THREADS, 0, stream>>>(x, Wc, bc, Wh, bh, Wm, bm,
                                                 Wo, bo, out);
}